// Round 3
// baseline (81.629 us; speedup 1.0000x reference)
//
#include <hip/hip_runtime.h>

// Tropical (max-plus) linear layer:
//   out[b, j] = max_k (x[b,k] + w[j,k]) + bias[j]   if any product > -1e38
//             = -1e38                                otherwise
// x: [4096, 256] f32, w: [256, 256] f32, bias: [256] f32, out: [4096, 256] f32
//
// R6 structure: w-in-VGPR + x via wave-uniform VECTOR global loads (L1 bcast).
//  - R5 post-mortem: R3 (ds w + smem x) and R5 (ds-broadcast x + vgpr w) both
//    ~32us -> shared limiter. R5's own LDS floor was 10.2us/CU (2048 bcast
//    b128 reads x 12cyc) >> 5.1us VALU floor; plus uncoalesced w prologue.
//  - R6 hot loop: NO ds, NO smem. x offset laundered through asm("+v") so the
//    compiler emits global_load_dwordx4 (vmcnt, 1 cacheline/instr, L1-hot
//    16KB/block x 2 blocks = 32KB = L1). w resident: 16 float4 = 64 VGPRs.
//    96 VALU per 8 loads.
//  - LDS only for the single-phase 8-way k-combine: part[8][16][128] = 64KB.
//  - unroll 1 on row loop caps xv in flight: ~112 VGPR < 128 (launch_bounds
//    512,4) -> 2 blocks/CU, 16 waves/CU, 4/SIMD.

#define TZERO -1e38f

constexpr int K    = 256;
constexpr int N    = 256;
constexpr int ROWS = 16;    // rows per block
constexpr int COLS = 128;   // cols per block (2 per lane)
constexpr int NT   = 512;   // 8 waves = 8 k-segments
constexpr int KSEG = 32;    // k-extent per wave

__global__ __launch_bounds__(NT, 4)
void tropical_kernel(const float* __restrict__ x, const float* __restrict__ w,
                     const float* __restrict__ bias, float* __restrict__ out)
{
    __shared__ float part[8][ROWS][COLS];   // 64 KB, only use of LDS

    const int t    = threadIdx.x;
    const int lane = t & 63;
    const int ws   = __builtin_amdgcn_readfirstlane(t >> 6);  // k-segment id
    const int row0 = blockIdx.x * ROWS;
    const int col0 = blockIdx.y * COLS;

    // ---- w fragments: 2 cols x 32 k = 16 float4 = 64 VGPRs, static indexing
    const float* w0 = w + (size_t)(col0 + lane) * K + ws * KSEG;
    const float* w1 = w0 + (size_t)64 * K;
    float4 wA[8], wB[8];
#pragma unroll
    for (int i = 0; i < 8; ++i) {
        wA[i] = *reinterpret_cast<const float4*>(w0 + 4 * i);
        wB[i] = *reinterpret_cast<const float4*>(w1 + 4 * i);
    }

    // ---- main loop: per row, 8 wave-uniform global float4 loads + 96 VALU
    const float* xbase = x + (size_t)row0 * K;   // SGPR base

#pragma unroll 1
    for (int r = 0; r < ROWS; ++r) {
        int off = r * K + ws * KSEG;
        // launder the offset into an opaque VGPR: compiler can't prove
        // uniformity -> emits global_load_dwordx4 (VMEM/L1 broadcast path),
        // NOT s_load (R4's SGPR blowup) and NOT ds_read (R5's LDS pipe).
        asm("" : "+v"(off));
        const float* xr = xbase + off;

        float a0 = -__builtin_inff();
        float a1 = -__builtin_inff();
#pragma unroll
        for (int i = 0; i < 8; ++i) {
            const float4 xv = *reinterpret_cast<const float4*>(xr + 4 * i);
            const float s0 = xv.x + wA[i].x;
            const float s1 = xv.y + wA[i].y;
            const float s2 = xv.z + wA[i].z;
            const float s3 = xv.w + wA[i].w;
            a0 = fmaxf(fmaxf(a0, s0), s1);   // v_max3_f32
            a0 = fmaxf(fmaxf(a0, s2), s3);   // v_max3_f32
            const float u0 = xv.x + wB[i].x;
            const float u1 = xv.y + wB[i].y;
            const float u2 = xv.z + wB[i].z;
            const float u3 = xv.w + wB[i].w;
            a1 = fmaxf(fmaxf(a1, u0), u1);
            a1 = fmaxf(fmaxf(a1, u2), u3);
        }
        part[ws][r][lane]      = a0;   // consecutive banks, conflict-free
        part[ws][r][64 + lane] = a1;
    }

    __syncthreads();

    // ---- epilogue: 8-way combine across k-segments, bias, guard, store
    {
        const int c  = t & 127;
        const int rb = t >> 7;             // 0..3
        const float bj = bias[col0 + c];
#pragma unroll
        for (int j = 0; j < 4; ++j) {
            const int r = rb + 4 * j;
            float v = part[0][r][c];
#pragma unroll
            for (int s = 1; s < 8; ++s) v = fmaxf(v, part[s][r][c]);
            out[(size_t)(row0 + r) * N + col0 + c] = (v > TZERO) ? v + bj : TZERO;
        }
    }
}

extern "C" void kernel_launch(void* const* d_in, const int* in_sizes, int n_in,
                              void* d_out, int out_size, void* d_ws, size_t ws_size,
                              hipStream_t stream) {
    const float* x  = (const float*)d_in[0];
    const float* w  = (const float*)d_in[1];
    const float* b  = (const float*)d_in[2];
    float* out      = (float*)d_out;

    dim3 grid(4096 / ROWS, N / COLS);   // (256, 2) = 512 blocks, 8 waves each
    tropical_kernel<<<grid, NT, 0, stream>>>(x, w, b, out);
}

// Round 4
// 72.247 us; speedup vs baseline: 1.1299x; 1.1299x over previous
//
#include <hip/hip_runtime.h>

// Tropical (max-plus) linear layer:
//   out[b, j] = max_k (x[b,k] + w[j,k]) + bias[j]   if any product > -1e38
//             = -1e38                                otherwise
// x: [4096, 256] f32, w: [256, 256] f32, bias: [256] f32, out: [4096, 256] f32
//
// R7: two kernels.
//  1) transpose_w: w -> wT[K][N] in d_ws (LDS-tiled, coalesced both sides).
//     Kills the 1KB-stride w prologue every prior round paid (16 loads/wave
//     x 64 cachelines each -> ~16K TA lookups/CU).
//  2) tropical_kernel: w fragment loaded COALESCED from wT (lane=col, 64 b32
//     wave-requests). x via scalar loads: 8 float4 = 32 SGPRs per row,
//     manual 2-row double-buffer with named static buffers (R4 post-mortem:
//     128 SGPRs/pair + VGPR cap 64 -> wq spilled to scratch, 44MB writes).
//     Hot loop: NO ds_read, NO vmem - 96 VALU + 2 ds_write per row.
//     launch_bounds(512,2): worst-case reg pressure degrades occupancy
//     instead of spilling.

#define TZERO -1e38f

constexpr int K    = 256;
constexpr int N    = 256;
constexpr int ROWS = 16;    // rows per block
constexpr int COLS = 128;   // cols per block (2 per lane)
constexpr int NT   = 512;   // 8 waves = 8 k-segments
constexpr int KSEG = 32;    // k-extent per wave

// ---------------------------------------------------------------- transpose
__global__ __launch_bounds__(256)
void transpose_w(const float* __restrict__ w, float* __restrict__ wT)
{
    __shared__ float ls[64][65];          // +1 pad: conflict-free columns
    const int bi = blockIdx.x * 64;       // row block in w  (cols of wT)
    const int bj = blockIdx.y * 64;       // col block in w  (rows of wT)
    const int t  = threadIdx.x;
    const int lr = t >> 4;                // 0..15
    const int lc = (t & 15) * 4;          // 0,4,...,60

#pragma unroll
    for (int i = 0; i < 4; ++i) {         // coalesced read of w rows
        const int r = lr + i * 16;
        const float4 v =
            *reinterpret_cast<const float4*>(w + (size_t)(bi + r) * K + bj + lc);
        ls[r][lc + 0] = v.x; ls[r][lc + 1] = v.y;
        ls[r][lc + 2] = v.z; ls[r][lc + 3] = v.w;
    }
    __syncthreads();
#pragma unroll
    for (int i = 0; i < 4; ++i) {         // coalesced write of wT rows
        const int kk = lr + i * 16;       // k index within tile
        float4 v;
        v.x = ls[lc + 0][kk]; v.y = ls[lc + 1][kk];
        v.z = ls[lc + 2][kk]; v.w = ls[lc + 3][kk];
        *reinterpret_cast<float4*>(wT + (size_t)(bj + kk) * N + bi + lc) = v;
    }
}

// ---------------------------------------------------------------- main
__device__ __forceinline__ void row_compute(
    const float4 (&buf)[8], const float (&wA)[KSEG], const float (&wB)[KSEG],
    float& a0, float& a1)
{
    float p0 = -__builtin_inff(), p1 = -__builtin_inff();
    float q0 = -__builtin_inff(), q1 = -__builtin_inff();
#pragma unroll
    for (int i = 0; i < 8; ++i) {
        const float4 xv = buf[i];         // SGPR-resident x (wave-uniform)
        p0 = fmaxf(fmaxf(p0, xv.x + wA[4 * i + 0]), xv.y + wA[4 * i + 1]);
        p1 = fmaxf(fmaxf(p1, xv.z + wA[4 * i + 2]), xv.w + wA[4 * i + 3]);
        q0 = fmaxf(fmaxf(q0, xv.x + wB[4 * i + 0]), xv.y + wB[4 * i + 1]);
        q1 = fmaxf(fmaxf(q1, xv.z + wB[4 * i + 2]), xv.w + wB[4 * i + 3]);
    }
    a0 = fmaxf(p0, p1);
    a1 = fmaxf(q0, q1);
}

__global__ __launch_bounds__(NT, 2)
void tropical_kernel(const float* __restrict__ x, const float* __restrict__ wT,
                     const float* __restrict__ bias, float* __restrict__ out)
{
    __shared__ float part[8][ROWS][COLS];   // 64 KB, only LDS use

    const int t    = threadIdx.x;
    const int lane = t & 63;
    const int ws   = __builtin_amdgcn_readfirstlane(t >> 6);  // k-segment id
    const int row0 = blockIdx.x * ROWS;
    const int col0 = blockIdx.y * COLS;

    // ---- w fragments from wT: coalesced (lane = col), 64 b32 wave-requests
    const int k0 = ws * KSEG;
    float wA[KSEG], wB[KSEG];
    {
        const float* wp = wT + (size_t)k0 * N + col0 + lane;
#pragma unroll
        for (int k = 0; k < KSEG; ++k) {
            wA[k] = wp[(size_t)k * N];        // col0 + lane
            wB[k] = wp[(size_t)k * N + 64];   // col0 + 64 + lane
        }
    }

    // ---- x through the scalar path: 8 float4 = 32 SGPRs per row,
    //      2-row double-buffer with NAMED static buffers (no runtime index)
    const float* xp = x + (size_t)row0 * K + k0;   // wave-uniform base

    float4 bA[8], bB[8];
#pragma unroll
    for (int i = 0; i < 8; ++i)
        bA[i] = *reinterpret_cast<const float4*>(xp + 4 * i);   // row 0

    float a0, a1;
#pragma unroll 1
    for (int r = 0; r < ROWS; r += 2) {
        // prefetch row r+1 while computing row r
#pragma unroll
        for (int i = 0; i < 8; ++i)
            bB[i] = *reinterpret_cast<const float4*>(xp + (r + 1) * K + 4 * i);

        row_compute(bA, wA, wB, a0, a1);
        part[ws][r][lane]      = a0;
        part[ws][r][64 + lane] = a1;

        if (r + 2 < ROWS) {
#pragma unroll
            for (int i = 0; i < 8; ++i)
                bA[i] = *reinterpret_cast<const float4*>(xp + (r + 2) * K + 4 * i);
        }

        row_compute(bB, wA, wB, a0, a1);
        part[ws][r + 1][lane]      = a0;
        part[ws][r + 1][64 + lane] = a1;
    }

    __syncthreads();

    // ---- epilogue: 8-way k-segment combine, bias, guard, coalesced store
    {
        const int c  = t & 127;
        const int rb = t >> 7;             // 0..3
        const float bj = bias[col0 + c];
#pragma unroll
        for (int j = 0; j < 4; ++j) {
            const int r = rb + 4 * j;
            float v = part[0][r][c];
#pragma unroll
            for (int s = 1; s < 8; ++s) v = fmaxf(v, part[s][r][c]);
            out[(size_t)(row0 + r) * N + col0 + c] = (v > TZERO) ? v + bj : TZERO;
        }
    }
}

extern "C" void kernel_launch(void* const* d_in, const int* in_sizes, int n_in,
                              void* d_out, int out_size, void* d_ws, size_t ws_size,
                              hipStream_t stream) {
    const float* x  = (const float*)d_in[0];
    const float* w  = (const float*)d_in[1];
    const float* b  = (const float*)d_in[2];
    float* out      = (float*)d_out;
    float* wT       = (float*)d_ws;     // 256 KB scratch for transposed w

    dim3 tg(4, 4);                       // 16 tiles of 64x64
    transpose_w<<<tg, 256, 0, stream>>>(w, wT);

    dim3 grid(4096 / ROWS, N / COLS);    // (256, 2) = 512 blocks, 8 waves each
    tropical_kernel<<<grid, NT, 0, stream>>>(x, wT, b, out);
}

// Round 6
// 72.164 us; speedup vs baseline: 1.1312x; 1.0012x over previous
//
#include <hip/hip_runtime.h>

// Tropical (max-plus) linear layer:
//   out[b, j] = max_k (x[b,k] + w[j,k]) + bias[j]   if any product > -1e38
//             = -1e38                                otherwise
// x: [4096, 256] f32, w: [256, 256] f32, bias: [256] f32, out: [4096, 256] f32
//
// R9 = R8 resubmitted verbatim (R8 bench died on container acquisition, not
// on the kernel: no pytest/absmax/profile data was produced).
//
// R8 = R7 structure + packed-fp32 adds in the hot loop.
//  - R7 post-mortem: FOUR different memory-path structures all land at
//    ~31-33us residual; w-prologue fix (wT) changed nothing. The invariant is
//    the VALU instruction count (~6.3M wave-instrs). At low SCLK (short
//    kernels after a memory-bound fill never ramp the core clock) that is
//    ~26-31us -- the observed residual. Only lever left: fewer VALU instrs.
//  - v_pk_add_f32 (VOP3P, CDNA2+) does 2 f32 adds/instr; no packed f32 max
//    exists, so: per 4 k-elems per col, 6 instr -> 2 pk_add + 2 v_max3 = 4
//    (-33% hot-loop VALU). x passed as SGPR pair ("s" constraint, one scalar
//    source is legal in VOP3P; halves of the s_load quad are even-aligned).
//    The "s" constraint is load-bearing: a VGPR-source fallback would add
//    32 v_mov/row and the net gain would be zero.
//  - Everything else identical to R7 (passed, absmax 0): transpose_w
//    pre-kernel, coalesced wT loads, x via scalar path double-buffer,
//    LDS only for the 8-way k-segment combine.

#define TZERO -1e38f

constexpr int K    = 256;
constexpr int N    = 256;
constexpr int ROWS = 16;    // rows per block
constexpr int COLS = 128;   // cols per block (2 per lane)
constexpr int NT   = 512;   // 8 waves = 8 k-segments
constexpr int KSEG = 32;    // k-extent per wave

typedef float f32x2 __attribute__((ext_vector_type(2)));

// ---------------------------------------------------------------- transpose
__global__ __launch_bounds__(256)
void transpose_w(const float* __restrict__ w, float* __restrict__ wT)
{
    __shared__ float ls[64][65];          // +1 pad: conflict-free columns
    const int bi = blockIdx.x * 64;       // row block in w  (cols of wT)
    const int bj = blockIdx.y * 64;       // col block in w  (rows of wT)
    const int t  = threadIdx.x;
    const int lr = t >> 4;                // 0..15
    const int lc = (t & 15) * 4;          // 0,4,...,60

#pragma unroll
    for (int i = 0; i < 4; ++i) {         // coalesced read of w rows
        const int r = lr + i * 16;
        const float4 v =
            *reinterpret_cast<const float4*>(w + (size_t)(bi + r) * K + bj + lc);
        ls[r][lc + 0] = v.x; ls[r][lc + 1] = v.y;
        ls[r][lc + 2] = v.z; ls[r][lc + 3] = v.w;
    }
    __syncthreads();
#pragma unroll
    for (int i = 0; i < 4; ++i) {         // coalesced write of wT rows
        const int kk = lr + i * 16;       // k index within tile
        float4 v;
        v.x = ls[lc + 0][kk]; v.y = ls[lc + 1][kk];
        v.z = ls[lc + 2][kk]; v.w = ls[lc + 3][kk];
        *reinterpret_cast<float4*>(wT + (size_t)(bj + kk) * N + bi + lc) = v;
    }
}

// ---------------------------------------------------------------- main
// packed add: d = {xs.x + wv.x, xs.y + wv.y}; xs is wave-uniform (SGPR pair)
__device__ __forceinline__ f32x2 pk_add_sv(f32x2 xs, f32x2 wv)
{
    f32x2 r;
    asm("v_pk_add_f32 %0, %1, %2" : "=v"(r) : "s"(xs), "v"(wv));
    return r;
}

__device__ __forceinline__ void row_compute(
    const float4 (&buf)[8], const f32x2 (&wA)[16], const f32x2 (&wB)[16],
    float& a0, float& a1)
{
    float p0 = -__builtin_inff(), p1 = -__builtin_inff();
    float q0 = -__builtin_inff(), q1 = -__builtin_inff();
#pragma unroll
    for (int i = 0; i < 8; ++i) {
        const f32x2 xlo = {buf[i].x, buf[i].y};   // s[4i:4i+1], even-aligned
        const f32x2 xhi = {buf[i].z, buf[i].w};   // s[4i+2:4i+3], even-aligned
        const f32x2 r0 = pk_add_sv(xlo, wA[2 * i + 0]);
        const f32x2 r1 = pk_add_sv(xhi, wA[2 * i + 1]);
        p0 = fmaxf(fmaxf(p0, r0.x), r0.y);        // v_max3_f32
        p1 = fmaxf(fmaxf(p1, r1.x), r1.y);        // v_max3_f32
        const f32x2 r2 = pk_add_sv(xlo, wB[2 * i + 0]);
        const f32x2 r3 = pk_add_sv(xhi, wB[2 * i + 1]);
        q0 = fmaxf(fmaxf(q0, r2.x), r2.y);
        q1 = fmaxf(fmaxf(q1, r3.x), r3.y);
    }
    a0 = fmaxf(p0, p1);
    a1 = fmaxf(q0, q1);
}

__global__ __launch_bounds__(NT, 2)
void tropical_kernel(const float* __restrict__ x, const float* __restrict__ wT,
                     const float* __restrict__ bias, float* __restrict__ out)
{
    __shared__ float part[8][ROWS][COLS];   // 64 KB, only LDS use

    const int t    = threadIdx.x;
    const int lane = t & 63;
    const int ws   = __builtin_amdgcn_readfirstlane(t >> 6);  // k-segment id
    const int row0 = blockIdx.x * ROWS;
    const int col0 = blockIdx.y * COLS;

    // ---- w fragments from wT: coalesced (lane = col), packed as k-pairs
    //      so each f32x2 lands in an even-aligned VGPR pair for v_pk_add_f32
    const int k0 = ws * KSEG;
    f32x2 wA[16], wB[16];
    {
        const float* wp = wT + (size_t)k0 * N + col0 + lane;
#pragma unroll
        for (int i = 0; i < 16; ++i) {
            wA[i] = f32x2{wp[(size_t)(2 * i) * N],      wp[(size_t)(2 * i + 1) * N]};
            wB[i] = f32x2{wp[(size_t)(2 * i) * N + 64], wp[(size_t)(2 * i + 1) * N + 64]};
        }
    }

    // ---- x through the scalar path: 8 float4 = 32 SGPRs per row,
    //      2-row double-buffer with NAMED static buffers (no runtime index)
    const float* xp = x + (size_t)row0 * K + k0;   // wave-uniform base

    float4 bA[8], bB[8];
#pragma unroll
    for (int i = 0; i < 8; ++i)
        bA[i] = *reinterpret_cast<const float4*>(xp + 4 * i);   // row 0

    float a0, a1;
#pragma unroll 1
    for (int r = 0; r < ROWS; r += 2) {
        // prefetch row r+1 while computing row r
#pragma unroll
        for (int i = 0; i < 8; ++i)
            bB[i] = *reinterpret_cast<const float4*>(xp + (r + 1) * K + 4 * i);

        row_compute(bA, wA, wB, a0, a1);
        part[ws][r][lane]      = a0;
        part[ws][r][64 + lane] = a1;

        if (r + 2 < ROWS) {
#pragma unroll
            for (int i = 0; i < 8; ++i)
                bA[i] = *reinterpret_cast<const float4*>(xp + (r + 2) * K + 4 * i);
        }

        row_compute(bB, wA, wB, a0, a1);
        part[ws][r + 1][lane]      = a0;
        part[ws][r + 1][64 + lane] = a1;
    }

    __syncthreads();

    // ---- epilogue: 8-way k-segment combine, bias, guard, coalesced store
    {
        const int c  = t & 127;
        const int rb = t >> 7;             // 0..3
        const float bj = bias[col0 + c];
#pragma unroll
        for (int j = 0; j < 4; ++j) {
            const int r = rb + 4 * j;
            float v = part[0][r][c];
#pragma unroll
            for (int s = 1; s < 8; ++s) v = fmaxf(v, part[s][r][c]);
            out[(size_t)(row0 + r) * N + col0 + c] = (v > TZERO) ? v + bj : TZERO;
        }
    }
}

extern "C" void kernel_launch(void* const* d_in, const int* in_sizes, int n_in,
                              void* d_out, int out_size, void* d_ws, size_t ws_size,
                              hipStream_t stream) {
    const float* x  = (const float*)d_in[0];
    const float* w  = (const float*)d_in[1];
    const float* b  = (const float*)d_in[2];
    float* out      = (float*)d_out;
    float* wT       = (float*)d_ws;     // 256 KB scratch for transposed w

    dim3 tg(4, 4);                       // 16 tiles of 64x64
    transpose_w<<<tg, 256, 0, stream>>>(w, wT);

    dim3 grid(4096 / ROWS, N / COLS);    // (256, 2) = 512 blocks, 8 waves each
    tropical_kernel<<<grid, NT, 0, stream>>>(x, wT, b, out);
}